// Round 12
// baseline (114.554 us; speedup 1.0000x reference)
//
#include <hip/hip_runtime.h>

constexpr int KWIN = 100;
constexpr int HK   = 50;
constexpr int TSUB = 32;    // frames per thread (8 main batches of 4)
constexpr int MB   = 4;     // outputs per batch -> 12 loads per batch
constexpr int PB   = 10;    // prime batch -> 10 batches

template <bool REFLECT>
__device__ __forceinline__ int tidx(int t) {
    if constexpr (REFLECT) {
        constexpr int T = 16384;
        t = (t < 0) ? -t : t;
        return (t >= T) ? (2 * T - 2 - t) : t;
    }
    return t;   // interior chunk: linear addressing
}

template <bool REFLECT>
__device__ __forceinline__ void load_prime(const float* __restrict__ xb,
                                           const int t0, const int k,
                                           float p[PB]) {
    #pragma unroll
    for (int j = 0; j < PB; ++j)
        p[j] = xb[(size_t)tidx<REFLECT>(t0 - HK + k * PB + j) * 128];
}

__device__ __forceinline__ void acc_prime(const float p[PB],
                                          float& sx, float& sq) {
    #pragma unroll
    for (int j = 0; j < PB; ++j) {
        sx += p[j];
        sq  = fmaf(p[j], p[j], sq);
    }
}

template <bool REFLECT>
__device__ __forceinline__ void load_main(const float* __restrict__ xb,
                                          const int t0, const int tb,
                                          float c[MB], float o[MB], float g[MB]) {
    #pragma unroll
    for (int j = 0; j < MB; ++j) {
        const int t = t0 + tb + j;
        c[j] = xb[(size_t)t * 128];                       // x[t] never reflects
        o[j] = xb[(size_t)tidx<REFLECT>(t - HK) * 128];   // x[t-50]
        g[j] = xb[(size_t)tidx<REFLECT>(t + HK) * 128];   // x[t+50]
    }
}

__device__ __forceinline__ void compute_main(float* __restrict__ ob,
                                             const int t0, const int tb,
                                             const float c[MB], const float o[MB],
                                             const float g[MB],
                                             float& sx, float& sq) {
    const float invK   = 1.0f / (float)KWIN;
    const float invKm1 = 1.0f / (float)(KWIN - 1);
    const float fK     = (float)KWIN;
    #pragma unroll
    for (int j = 0; j < MB; ++j) {
        const float m  = sx * invK;
        const float va = fmaxf((sq - fK * m * m) * invKm1, 1e-24f);
        const float rs = __builtin_amdgcn_rsqf(va);       // v_rsq_f32
        __builtin_nontemporal_store((c[j] - m) * rs,
                                    &ob[(size_t)(t0 + tb + j) * 128]);
        sx += g[j] - o[j];
        sq += g[j] * g[j] - o[j] * o[j];
    }
}

template <bool REFLECT>
__device__ __forceinline__ void run_chunk(
    const float* __restrict__ xb, float* __restrict__ ob, const int t0)
{
    float sx = 0.f, sq = 0.f;

    // ---- prime: 10 batches of 10, software-pipelined 2-deep ----
    {
        float pa[PB], pb_[PB];
        load_prime<REFLECT>(xb, t0, 0, pa);
        load_prime<REFLECT>(xb, t0, 1, pb_);
        acc_prime(pa, sx, sq);  load_prime<REFLECT>(xb, t0, 2, pa);
        acc_prime(pb_, sx, sq); load_prime<REFLECT>(xb, t0, 3, pb_);
        acc_prime(pa, sx, sq);  load_prime<REFLECT>(xb, t0, 4, pa);
        acc_prime(pb_, sx, sq); load_prime<REFLECT>(xb, t0, 5, pb_);
        acc_prime(pa, sx, sq);  load_prime<REFLECT>(xb, t0, 6, pa);
        acc_prime(pb_, sx, sq); load_prime<REFLECT>(xb, t0, 7, pb_);
        acc_prime(pa, sx, sq);  load_prime<REFLECT>(xb, t0, 8, pa);
        acc_prime(pb_, sx, sq); load_prime<REFLECT>(xb, t0, 9, pb_);
        acc_prime(pa, sx, sq);
        acc_prime(pb_, sx, sq);
    }

    // ---- main: 8 batches of 4 outputs, 2-deep: 24 loads in flight ----
    float cA[MB], oA[MB], gA[MB], cB[MB], oB[MB], gB[MB];
    load_main<REFLECT>(xb, t0, 0 * MB, cA, oA, gA);
    load_main<REFLECT>(xb, t0, 1 * MB, cB, oB, gB);
    compute_main(ob, t0, 0 * MB, cA, oA, gA, sx, sq);
    load_main<REFLECT>(xb, t0, 2 * MB, cA, oA, gA);
    compute_main(ob, t0, 1 * MB, cB, oB, gB, sx, sq);
    load_main<REFLECT>(xb, t0, 3 * MB, cB, oB, gB);
    compute_main(ob, t0, 2 * MB, cA, oA, gA, sx, sq);
    load_main<REFLECT>(xb, t0, 4 * MB, cA, oA, gA);
    compute_main(ob, t0, 3 * MB, cB, oB, gB, sx, sq);
    load_main<REFLECT>(xb, t0, 5 * MB, cB, oB, gB);
    compute_main(ob, t0, 4 * MB, cA, oA, gA, sx, sq);
    load_main<REFLECT>(xb, t0, 6 * MB, cA, oA, gA);
    compute_main(ob, t0, 5 * MB, cB, oB, gB, sx, sq);
    load_main<REFLECT>(xb, t0, 7 * MB, cB, oB, gB);
    compute_main(ob, t0, 6 * MB, cA, oA, gA, sx, sq);
    compute_main(ob, t0, 7 * MB, cB, oB, gB, sx, sq);
}

__global__ __launch_bounds__(256, 8) void man_kernel(
    const float* __restrict__ x, float* __restrict__ out)
{
    constexpr int T = 16384, D = 128;

    const int i    = blockIdx.x;                  // 0..2047
    const int bb   = (i & 7) * 256 + (i >> 3);    // XCD (i&7) owns batch b
    const int b    = bb >> 8;                     // 0..7
    const int pair = bb & 255;                    // pair of adjacent chunks
    const int w    = threadIdx.x >> 7;            // 0..1 chunk within pair
    const int tid  = threadIdx.x & 127;           // d column
    const int t0   = (pair * 2 + w) * TSUB;

    const float* __restrict__ xb = x   + (size_t)b * T * D + tid;
    float*       __restrict__ ob = out + (size_t)b * T * D + tid;

    if (t0 >= HK && t0 + TSUB - 1 + HK < T) {
        run_chunk<false>(xb, ob, t0);
    } else {
        run_chunk<true>(xb, ob, t0);
    }
}

extern "C" void kernel_launch(void* const* d_in, const int* in_sizes, int n_in,
                              void* d_out, int out_size, void* d_ws, size_t ws_size,
                              hipStream_t stream) {
    (void)in_sizes; (void)n_in; (void)d_ws; (void)ws_size; (void)out_size;
    const float* x = (const float*)d_in[0];
    float* out = (float*)d_out;
    // 8 b * 512 chunks * 128 d = 524288 threads = 2048 blocks * 256
    man_kernel<<<dim3(2048), dim3(256), 0, stream>>>(x, out);
}

// Round 13
// 30.000 us; speedup vs baseline: 3.8185x; 3.8185x over previous
//
#include <hip/hip_runtime.h>

constexpr int KWIN = 100;
constexpr int HK   = 50;
constexpr int TSUB = 64;    // frames per thread (8 main batches of 8)
constexpr int MB   = 8;     // outputs per batch -> 16 loads per batch (in+out)
constexpr int PB   = 25;    // prime batch

template <bool REFLECT>
__device__ __forceinline__ int tidx(int t) {
    if constexpr (REFLECT) {
        constexpr int T = 16384;
        t = (t < 0) ? -t : t;
        return (t >= T) ? (2 * T - 2 - t) : t;
    }
    return t;   // interior chunk: linear addressing
}

template <bool REFLECT>
__device__ __forceinline__ void run_chunk(
    const float* __restrict__ xb, float* __restrict__ ob, const int t0)
{
    float ring[HK];           // frames t0+k at slot k%50 — all indices static
    float sx = 0.f, sq = 0.f;

    // ---- prime: frames [t0-50, t0+49]; low half sums-only, high half -> ring.
    // 4 batches of 25, software-pipelined 2-deep.
    {
        float la[PB], lb[PB];
        #pragma unroll
        for (int j = 0; j < PB; ++j)      // low batch 0: t0-50 .. t0-26
            la[j] = xb[(size_t)tidx<REFLECT>(t0 - HK + j) * 128];
        #pragma unroll
        for (int j = 0; j < PB; ++j)      // low batch 1: t0-25 .. t0-1
            lb[j] = xb[(size_t)tidx<REFLECT>(t0 - PB + j) * 128];
        #pragma unroll
        for (int j = 0; j < PB; ++j) { sx += la[j]; sq = fmaf(la[j], la[j], sq); }
        #pragma unroll
        for (int j = 0; j < PB; ++j)      // high batch 0 -> ring[0..24]
            ring[j] = xb[(size_t)tidx<REFLECT>(t0 + j) * 128];
        #pragma unroll
        for (int j = 0; j < PB; ++j) { sx += lb[j]; sq = fmaf(lb[j], lb[j], sq); }
        #pragma unroll
        for (int j = 0; j < PB; ++j)      // high batch 1 -> ring[25..49]
            ring[PB + j] = xb[(size_t)tidx<REFLECT>(t0 + PB + j) * 128];
        #pragma unroll
        for (int j = 0; j < PB; ++j) { sx += ring[j]; sq = fmaf(ring[j], ring[j], sq); }
        #pragma unroll
        for (int j = 0; j < PB; ++j) { sx += ring[PB + j]; sq = fmaf(ring[PB + j], ring[PB + j], sq); }
    }

    const float invK   = 1.0f / (float)KWIN;
    const float invKm1 = 1.0f / (float)(KWIN - 1);
    const float fK     = (float)KWIN;

    // ---- main: 8 batches of 8 outputs, 2-deep pipeline.
    // Per output k: in = x[t0+k+50] (load), out = x[t0+k-50] (load),
    // center = ring[k%50] (register), then ring[k%50] = in.
    float inA[MB], outA[MB], inB[MB], outB[MB];

#define LOADB(IN, OUT, KB)                                                    \
    {                                                                         \
        _Pragma("unroll")                                                     \
        for (int j = 0; j < MB; ++j) {                                        \
            const int t = t0 + (KB) + j;                                      \
            IN[j]  = xb[(size_t)tidx<REFLECT>(t + HK) * 128];                 \
            OUT[j] = xb[(size_t)tidx<REFLECT>(t - HK) * 128];                 \
        }                                                                     \
    }

#define COMPUTEB(IN, OUT, KB)                                                 \
    {                                                                         \
        _Pragma("unroll")                                                     \
        for (int j = 0; j < MB; ++j) {                                        \
            const int k = (KB) + j;                                           \
            const float c  = ring[k % HK];                                    \
            const float m  = sx * invK;                                       \
            const float va = fmaxf((sq - fK * m * m) * invKm1, 1e-24f);       \
            const float rs = __builtin_amdgcn_rsqf(va);                       \
            __builtin_nontemporal_store((c - m) * rs,                         \
                                        &ob[(size_t)(t0 + k) * 128]);         \
            sx += IN[j] - OUT[j];                                             \
            sq += IN[j] * IN[j] - OUT[j] * OUT[j];                            \
            ring[k % HK] = IN[j];                                             \
        }                                                                     \
    }

    LOADB(inA, outA, 0 * MB);
    LOADB(inB, outB, 1 * MB);
    COMPUTEB(inA, outA, 0 * MB);
    LOADB(inA, outA, 2 * MB);
    COMPUTEB(inB, outB, 1 * MB);
    LOADB(inB, outB, 3 * MB);
    COMPUTEB(inA, outA, 2 * MB);
    LOADB(inA, outA, 4 * MB);
    COMPUTEB(inB, outB, 3 * MB);
    LOADB(inB, outB, 5 * MB);
    COMPUTEB(inA, outA, 4 * MB);
    LOADB(inA, outA, 6 * MB);
    COMPUTEB(inB, outB, 5 * MB);
    LOADB(inB, outB, 7 * MB);
    COMPUTEB(inA, outA, 6 * MB);
    COMPUTEB(inB, outB, 7 * MB);

#undef LOADB
#undef COMPUTEB
}

__global__ __launch_bounds__(256, 2) void man_kernel(
    const float* __restrict__ x, float* __restrict__ out)
{
    constexpr int T = 16384, D = 128;

    const int i   = blockIdx.x;                  // 0..1023
    const int bb  = (i & 7) * 128 + (i >> 3);    // XCD (i&7) owns batch b
    const int b   = bb >> 7;                     // 0..7
    const int seg = bb & 127;                    // pair of adjacent chunks
    const int w   = threadIdx.x >> 7;            // 0..1 chunk within pair
    const int tid = threadIdx.x & 127;           // d column
    const int t0  = (seg * 2 + w) * TSUB;

    const float* __restrict__ xb = x   + (size_t)b * T * D + tid;
    float*       __restrict__ ob = out + (size_t)b * T * D + tid;

    if (t0 >= HK && t0 + TSUB - 1 + HK < T) {
        run_chunk<false>(xb, ob, t0);
    } else {
        run_chunk<true>(xb, ob, t0);
    }
}

extern "C" void kernel_launch(void* const* d_in, const int* in_sizes, int n_in,
                              void* d_out, int out_size, void* d_ws, size_t ws_size,
                              hipStream_t stream) {
    (void)in_sizes; (void)n_in; (void)d_ws; (void)ws_size; (void)out_size;
    const float* x = (const float*)d_in[0];
    float* out = (float*)d_out;
    // 8 b * 256 chunks * 128 d = 262144 threads = 1024 blocks * 256
    man_kernel<<<dim3(1024), dim3(256), 0, stream>>>(x, out);
}